// Round 1
// baseline (1199.731 us; speedup 1.0000x reference)
//
#include <hip/hip_runtime.h>
#include <hip/hip_bf16.h>

#define B_ 4
#define H_ 32
#define S_ 2048
#define D_ 128
#define DM_ 4096
#define BH_ (B_*H_)
#define M_ (B_*S_)   // 8192 rows of final GEMM

typedef short bf16x8 __attribute__((ext_vector_type(8)));
typedef float f32x4 __attribute__((ext_vector_type(4)));

__device__ __forceinline__ float phi_f(float x) {
    // elu(x)+1
    return x > 0.f ? x + 1.f : __expf(x);
}

__device__ __forceinline__ void gl_lds16(void* lds_uniform, const void* gptr) {
    __builtin_amdgcn_global_load_lds(
        (const __attribute__((address_space(1))) void*)gptr,
        (__attribute__((address_space(3))) void*)lds_uniform,
        16, 0, 0);
}

// ---------------------------------------------------------------------------
// K1: memory[bh][k][v] = sum_s phi(K[bh][s][k]) * V[bh][s][v]
//     norm[bh][k]      = sum_s phi(K[bh][s][k])
// grid (4 splits, 128 bh), block 256. Register tile 4k x 16v per thread.
// ---------------------------------------------------------------------------
__global__ __launch_bounds__(256) void k1_memory(
    const float* __restrict__ Kin, const float* __restrict__ Vin,
    float* __restrict__ mem, float* __restrict__ nrm)
{
    const int split = blockIdx.x;   // 0..3, 512 rows each
    const int bh = blockIdx.y;
    const int tid = threadIdx.x;
    const int kg = tid >> 3, vg = tid & 7;
    const int k0 = kg * 4;

    __shared__ float sK[8][128];
    __shared__ float sV[8][128];

    float acc[4][16];
#pragma unroll
    for (int i = 0; i < 4; ++i)
#pragma unroll
        for (int j = 0; j < 16; ++j) acc[i][j] = 0.f;
    float na[4] = {0.f, 0.f, 0.f, 0.f};

    const long base = (long)bh * S_ * D_ + (long)split * (S_/4) * D_;
    const float* Kp = Kin + base;
    const float* Vp = Vin + base;

    const int lrow = tid >> 5;          // 0..7
    const int lcol = (tid & 31) * 4;

    for (int c = 0; c < (S_/4)/8; ++c) {   // 64 chunks of 8 rows
        float4 kv = *(const float4*)(Kp + (long)(c*8 + lrow)*D_ + lcol);
        float4 vv = *(const float4*)(Vp + (long)(c*8 + lrow)*D_ + lcol);
        float4 pk = make_float4(phi_f(kv.x), phi_f(kv.y), phi_f(kv.z), phi_f(kv.w));
        __syncthreads();                   // previous iter readers done
        *(float4*)&sK[lrow][lcol] = pk;
        *(float4*)&sV[lrow][lcol] = vv;
        __syncthreads();
#pragma unroll
        for (int s = 0; s < 8; ++s) {
            float a[4];
            *(float4*)a = *(const float4*)&sK[s][k0];
            float bb[16];
#pragma unroll
            for (int j = 0; j < 4; ++j)
                *(float4*)&bb[j*4] = *(const float4*)&sV[s][vg*4 + j*32];
            if (vg == 0) {
#pragma unroll
                for (int i = 0; i < 4; ++i) na[i] += a[i];
            }
#pragma unroll
            for (int i = 0; i < 4; ++i)
#pragma unroll
                for (int j = 0; j < 16; ++j)
                    acc[i][j] += a[i] * bb[j];
        }
    }
    float* mp = mem + (long)bh * D_ * D_;
#pragma unroll
    for (int i = 0; i < 4; ++i)
#pragma unroll
        for (int j = 0; j < 16; ++j) {
            int v = vg*4 + (j>>2)*32 + (j&3);
            atomicAdd(&mp[(k0+i)*D_ + v], acc[i][j]);
        }
    if (vg == 0) {
        float* np = nrm + bh * D_;
#pragma unroll
        for (int i = 0; i < 4; ++i) atomicAdd(&np[k0+i], na[i]);
    }
}

// ---------------------------------------------------------------------------
// K2: retrieved = phi(Q) @ mem ; denom = phi(Q)·norm ;
//     attn = gw*retrieved/denom + lw*local ; write bf16 to [B,S,H*D]
// grid (64 s-chunks of 32 rows, 128 bh), block 256.
// mem rows streamed from global (L2-resident), phi(Q) staged in LDS.
// ---------------------------------------------------------------------------
__global__ __launch_bounds__(256) void k2_retrieve(
    const float* __restrict__ Qin, const float* __restrict__ Lin,
    const float* __restrict__ bal,
    const float* __restrict__ mem, const float* __restrict__ nrm,
    __hip_bfloat16* __restrict__ attnB)
{
    const int sc = blockIdx.x;    // 0..63
    const int bh = blockIdx.y;
    const int b = bh >> 5, h = bh & 31;
    const int tid = threadIdx.x;

    __shared__ float sQ[32][128];
    __shared__ float sN[128];
    __shared__ float sDenP[32][8];
    __shared__ float sDen[32];

    const float* Qp = Qin + (long)bh*S_*D_ + (long)sc*32*D_;
    const float* Lp = Lin + (long)bh*S_*D_ + (long)sc*32*D_;
    const float* mp = mem + (long)bh*D_*D_;

#pragma unroll
    for (int i = 0; i < 4; ++i) {
        int c = i*256 + tid;               // float4 chunk 0..1023
        float4 q = *(const float4*)(Qp + (long)c*4);
        float4 p = make_float4(phi_f(q.x), phi_f(q.y), phi_f(q.z), phi_f(q.w));
        ((float4*)sQ)[c] = p;
    }
    if (tid < 128) sN[tid] = nrm[bh*D_ + tid];
    __syncthreads();

    {
        int row = tid >> 3, pt = tid & 7;
        float p = 0.f;
#pragma unroll
        for (int kk = 0; kk < 16; ++kk) {
            int k = pt*16 + kk;
            p += sQ[row][k] * sN[k];
        }
        sDenP[row][pt] = p;
    }
    __syncthreads();
    if (tid < 32) {
        float d = 0.f;
#pragma unroll
        for (int j = 0; j < 8; ++j) d += sDenP[tid][j];
        sDen[tid] = d;
    }
    __syncthreads();

    const int vg = tid & 31, rg = tid >> 5;
    const int v0 = vg*4, r0 = rg*4;
    float acc[4][4];
#pragma unroll
    for (int r = 0; r < 4; ++r)
#pragma unroll
        for (int j = 0; j < 4; ++j) acc[r][j] = 0.f;

#pragma unroll 8
    for (int k = 0; k < 128; ++k) {
        float4 m = *(const float4*)(mp + k*D_ + v0);
#pragma unroll
        for (int r = 0; r < 4; ++r) {
            float q = sQ[r0+r][k];
            acc[r][0] += q*m.x; acc[r][1] += q*m.y;
            acc[r][2] += q*m.z; acc[r][3] += q*m.w;
        }
    }

    float bv = bal[h];
    float gw = 1.f/(1.f+__expf(-bv));
    float lw = 1.f/(1.f+__expf(-(1.f-bv)));
#pragma unroll
    for (int r = 0; r < 4; ++r) {
        int row = r0 + r;
        float scale = gw / sDen[row];
        float4 lv = *(const float4*)(Lp + (long)row*D_ + v0);
        float o0 = acc[r][0]*scale + lw*lv.x;
        float o1 = acc[r][1]*scale + lw*lv.y;
        float o2 = acc[r][2]*scale + lw*lv.z;
        float o3 = acc[r][3]*scale + lw*lv.w;
        __hip_bfloat16 ob[4] = {__float2bfloat16(o0), __float2bfloat16(o1),
                                __float2bfloat16(o2), __float2bfloat16(o3)};
        long oidx = ((long)b*S_ + sc*32 + row)*DM_ + h*D_ + v0;
        *(uint2*)(attnB + oidx) = *(uint2*)ob;
    }
}

// ---------------------------------------------------------------------------
// w_o fp32 -> bf16
// ---------------------------------------------------------------------------
__global__ __launch_bounds__(256) void kconv(
    const float* __restrict__ w, __hip_bfloat16* __restrict__ wb)
{
    long i = ((long)blockIdx.x*256 + threadIdx.x)*4;
    float4 f = *(const float4*)(w + i);
    __hip_bfloat16 ob[4] = {__float2bfloat16(f.x), __float2bfloat16(f.y),
                            __float2bfloat16(f.z), __float2bfloat16(f.w)};
    *(uint2*)(wb + i) = *(uint2*)ob;
}

// ---------------------------------------------------------------------------
// K3: Y[8192,4096] = X[8192,4096] @ W[4096,4096]^T   (bf16 MFMA, fp32 out)
// m97-style: 128x128 tile, BK=32, global_load_lds width 16, 4 waves 2x2,
// each wave 4x4 tiles of 16x16x32.
// ---------------------------------------------------------------------------
#define BM 128
#define BN 128
#define BK 32

__global__ __launch_bounds__(256) void k3_gemm(
    const __hip_bfloat16* __restrict__ X,
    const __hip_bfloat16* __restrict__ W,
    float* __restrict__ Y)
{
    __shared__ alignas(16) __hip_bfloat16 sA[BM][BK];
    __shared__ alignas(16) __hip_bfloat16 sB[BN][BK];

    const int tid = threadIdx.x;
    const int wave = tid >> 6, lane = tid & 63;
    const int m0 = blockIdx.x * BM;
    const int n0 = blockIdx.y * BN;
    const int wm = (wave >> 1) * 64, wn = (wave & 1) * 64;
    const int lm = lane & 15, quad = lane >> 4;

    f32x4 acc[4][4];
#pragma unroll
    for (int i = 0; i < 4; ++i)
#pragma unroll
        for (int j = 0; j < 4; ++j) {
            f32x4 z = {0.f, 0.f, 0.f, 0.f};
            acc[i][j] = z;
        }

    const int c0 = wave*64 + lane;

    for (int kb = 0; kb < DM_; kb += BK) {
#pragma unroll
        for (int half = 0; half < 2; ++half) {
            int c = c0 + half*256;           // chunk 0..511 (16B chunks)
            int row = c >> 2, ko = (c & 3)*8;
            // LDS dest: wave-uniform base; lane lands at base + lane*16
            gl_lds16((void*)(&sA[0][0] + (wave*64 + half*256)*8),
                     (const void*)(X + (long)(m0+row)*DM_ + kb + ko));
            gl_lds16((void*)(&sB[0][0] + (wave*64 + half*256)*8),
                     (const void*)(W + (long)(n0+row)*DM_ + kb + ko));
        }
        __syncthreads();

        bf16x8 af[4], bf[4];
#pragma unroll
        for (int t = 0; t < 4; ++t) {
            af[t] = *(const bf16x8*)&sA[wm + t*16 + lm][quad*8];
            bf[t] = *(const bf16x8*)&sB[wn + t*16 + lm][quad*8];
        }
#pragma unroll
        for (int mt = 0; mt < 4; ++mt)
#pragma unroll
            for (int nt = 0; nt < 4; ++nt)
                acc[mt][nt] = __builtin_amdgcn_mfma_f32_16x16x32_bf16(
                    af[mt], bf[nt], acc[mt][nt], 0, 0, 0);
        __syncthreads();
    }

    // C/D layout: col = lane&15, row = quad*4 + reg
#pragma unroll
    for (int mt = 0; mt < 4; ++mt)
#pragma unroll
        for (int nt = 0; nt < 4; ++nt) {
            int col = n0 + wn + nt*16 + lm;
#pragma unroll
            for (int r = 0; r < 4; ++r) {
                int row = m0 + wm + mt*16 + quad*4 + r;
                Y[(long)row*DM_ + col] = acc[mt][nt][r];
            }
        }
}

// ---------------------------------------------------------------------------
extern "C" void kernel_launch(void* const* d_in, const int* in_sizes, int n_in,
                              void* d_out, int out_size, void* d_ws, size_t ws_size,
                              hipStream_t stream) {
    const float* Q   = (const float*)d_in[0];
    const float* K   = (const float*)d_in[1];
    const float* V   = (const float*)d_in[2];
    const float* L   = (const float*)d_in[3];
    const float* bal = (const float*)d_in[4];
    const float* Wo  = (const float*)d_in[5];
    float* Y = (float*)d_out;

    char* ws = (char*)d_ws;
    float* memory = (float*)ws;                                  // 8,388,608 B
    float* norm   = (float*)(ws + 8388608);                      //    65,536 B
    __hip_bfloat16* attnB = (__hip_bfloat16*)(ws + 8454144);     // 67,108,864 B
    __hip_bfloat16* woB   = (__hip_bfloat16*)(ws + 75563008);    // 33,554,432 B

    // zero the atomic accumulators (ws is poisoned 0xAA before every launch)
    hipMemsetAsync(memory, 0, 8454144, stream);

    k1_memory<<<dim3(4, BH_), 256, 0, stream>>>(K, V, memory, norm);
    kconv<<<DM_*DM_/4/256, 256, 0, stream>>>(Wo, woB);
    k2_retrieve<<<dim3(S_/32, BH_), 256, 0, stream>>>(Q, L, bal, memory, norm, attnB);
    k3_gemm<<<dim3(M_/BM, DM_/BN), 256, 0, stream>>>(attnB, woB, Y);
}